// Round 14
// baseline (134.391 us; speedup 1.0000x reference)
//
#include <hip/hip_runtime.h>
#include <hip/hip_bf16.h>
#include <cstdint>
#include <cstddef>

#define DEV static __device__ __forceinline__

typedef float f32x4 __attribute__((ext_vector_type(4)));
typedef __bf16 bf16x8 __attribute__((ext_vector_type(8)));
typedef __bf16 bf16x4 __attribute__((ext_vector_type(4)));

#define EXP2F(x) __builtin_amdgcn_exp2f(x)

union B8 {
  uint4 u4;
  uint32_t u[4];
  unsigned short s[8];
  bf16x8 v;
};
union B4 {
  uint2 u2;
  unsigned short s[4];
  bf16x4 v;
};

DEV unsigned short bfbits(float x) {
  union { __bf16 h; unsigned short s; } z; z.h = (__bf16)x; return z.s;
}
DEV uint32_t pk2(float x, float y) {
  union { __bf16 h[2]; uint32_t u; } z;
  z.h[0] = (__bf16)x; z.h[1] = (__bf16)y; return z.u;
}

DEV f32x4 mfma_bf16(bf16x8 a, bf16x8 b, f32x4 c) {
  return __builtin_amdgcn_mfma_f32_16x16x32_bf16(a, b, c, 0, 0, 0);
}

// async global->LDS, 16B per lane; LDS dest = wave-uniform base + lane*16
DEV void gload16(const void* g, void* l) {
  __builtin_amdgcn_global_load_lds(
      (const __attribute__((address_space(1))) void*)g,
      (__attribute__((address_space(3))) void*)l, 16, 0, 0);
}

// ===========================================================================
// cvt_all: fp32 -> bf16 for q,k,v (2^22 each) + wq,wk,wv,ow (2^20 each)
// into one contiguous 2^24-elem bf16 region. Grid 8192 x 256; thread: 8 elems.
// ===========================================================================
__global__ __launch_bounds__(256)
void cvt_all(const float* __restrict__ q, const float* __restrict__ k,
             const float* __restrict__ v,
             const float* __restrict__ wq, const float* __restrict__ wk,
             const float* __restrict__ wv, const float* __restrict__ ow,
             unsigned short* __restrict__ dst) {
  const int bid = blockIdx.x;
  const size_t base = ((size_t)bid << 11) + ((size_t)threadIdx.x << 3);
  const float* src;
  size_t rel;
  if (bid < 2048)      { src = q; rel = base; }
  else if (bid < 4096) { src = k; rel = base - (1u << 22); }
  else if (bid < 6144) { src = v; rel = base - (2u << 22); }
  else {
    const int wseg = (bid - 6144) >> 9;
    src = wseg == 0 ? wq : wseg == 1 ? wk : wseg == 2 ? wv : ow;
    rel = base & 1048575u;
  }
  float4 a0 = *(const float4*)(src + rel);
  float4 a1 = *(const float4*)(src + rel + 4);
  B8 p;
  p.u[0] = pk2(a0.x, a0.y); p.u[1] = pk2(a0.z, a0.w);
  p.u[2] = pk2(a1.x, a1.y); p.u[3] = pk2(a1.z, a1.w);
  *(uint4*)(dst + base) = p.u4;
}

// ===========================================================================
// Fused QKV GEMM v3: BM=64 x BN=128 x BK=64 + DOUBLE-BUFFERED gload_lds.
// LDS 48KB (As 2x8KB + Bs 2x16KB) -> 3 blocks/CU (>= measured residency, no
// r8 cliff). Per kt: issue gload(kt+1 -> buf^1), ds_read+MFMA(buf), ONE
// barrier (drain lands AFTER compute -> load latency hidden).
// Grid 1536 = 3 proj x (64 mb x 8 nb), XCD-bijective swizzle.
// ===========================================================================
__global__ __launch_bounds__(256, 2)
void gemm_qkv_b(const unsigned short* __restrict__ qb,
                const unsigned short* __restrict__ kb,
                const unsigned short* __restrict__ vb,
                const unsigned short* __restrict__ wqb,
                const unsigned short* __restrict__ wkb,
                const unsigned short* __restrict__ wvb,
                const float* __restrict__ bq, const float* __restrict__ bk,
                const float* __restrict__ bv,
                unsigned short* __restrict__ Qp, unsigned short* __restrict__ Kp,
                unsigned short* __restrict__ Vt) {
  const int K = 1024, N = 1024;
  __shared__ __align__(16) unsigned short As[2][64 * 64];    // 16KB
  __shared__ __align__(16) unsigned short Bs[2][128 * 64];   // 32KB
  const int bid = blockIdx.x;
  const int lbid = (bid & 7) * 192 + (bid >> 3);   // bijective, 1536 = 8*192
  const int proj = lbid >> 9;                       // 0..2
  const int t = lbid & 511;
  const int mb = t >> 3, nb = t & 7;
  const unsigned short* A  = proj == 0 ? qb  : proj == 1 ? kb  : vb;
  const unsigned short* Bw = proj == 0 ? wqb : proj == 1 ? wkb : wvb;
  const float* bias        = proj == 0 ? bq  : proj == 1 ? bk  : bv;
  const int tid = threadIdx.x;
  const int lane = tid & 63, w = tid >> 6;
  const int qc = lane & 15, g = lane >> 4;
  f32x4 acc[4][2] = {};

  const int lrow = lane >> 3, lg = lane & 7;
  const int gsrc = lg ^ lrow;                       // pre-swizzled source granule
  const unsigned short* ag = A  + (size_t)(mb * 64 + w * 16 + lrow) * K + gsrc * 8;
  const unsigned short* bg = Bw + (size_t)(nb * 128 + w * 32 + lrow) * K + gsrc * 8;

#define QSTAGE(BB, KT) do {                                                    \
    _Pragma("unroll")                                                          \
    for (int i_ = 0; i_ < 2; ++i_)                                             \
      gload16(ag + i_ * (8 * 1024) + (KT) * 64, &As[BB][(w * 16 + i_ * 8) * 64]); \
    _Pragma("unroll")                                                          \
    for (int i_ = 0; i_ < 4; ++i_)                                             \
      gload16(bg + i_ * (8 * 1024) + (KT) * 64, &Bs[BB][(w * 32 + i_ * 8) * 64]); \
  } while (0)

  QSTAGE(0, 0);
  __syncthreads();

  for (int kt = 0; kt < 16; ++kt) {
    const int cur = kt & 1;
    if (kt < 15) QSTAGE(cur ^ 1, kt + 1);   // prefetch; hides under compute

    B8 af[4][2], bfr[2][2];
#pragma unroll
    for (int mi = 0; mi < 4; ++mi)
#pragma unroll
      for (int kk = 0; kk < 2; ++kk) {
        const int row = mi * 16 + qc;
        const int slot = ((kk << 2) + g) ^ (row & 7);
        af[mi][kk].u4 = *(const uint4*)&As[cur][(row << 6) + (slot << 3)];
      }
#pragma unroll
    for (int ni = 0; ni < 2; ++ni)
#pragma unroll
      for (int kk = 0; kk < 2; ++kk) {
        const int row = w * 32 + ni * 16 + qc;
        const int slot = ((kk << 2) + g) ^ (row & 7);
        bfr[ni][kk].u4 = *(const uint4*)&Bs[cur][(row << 6) + (slot << 3)];
      }
#pragma unroll
    for (int kk = 0; kk < 2; ++kk)
#pragma unroll
      for (int mi = 0; mi < 4; ++mi)
#pragma unroll
        for (int ni = 0; ni < 2; ++ni)
          acc[mi][ni] = mfma_bf16(af[mi][kk].v, bfr[ni][kk].v, acc[mi][ni]);

    __syncthreads();   // drains prefetch vmcnt; buf^1 ready next iter
  }

  unsigned short* Cv = proj == 0 ? Qp : proj == 1 ? Kp : Vt;
  const bool vt_mode = (proj == 2);
#pragma unroll
  for (int ni = 0; ni < 2; ++ni) {
    const int col = nb * 128 + w * 32 + ni * 16 + qc;
    const float bv = bias[col];
#pragma unroll
    for (int mi = 0; mi < 4; ++mi) {
#pragma unroll
      for (int r = 0; r < 4; ++r) {
        const int row = mb * 64 + mi * 16 + g * 4 + r;
        const float val = acc[mi][ni][r] + bv;
        if (!vt_mode) {
          Cv[(size_t)row * N + col] = bfbits(val);
        } else {
          const int b = row >> 11, ss = row & 2047, hh = col >> 6, d = col & 63;
          Cv[((size_t)((b * 16 + hh) * 64 + d) << 11) + ss] = bfbits(val);
        }
      }
    }
  }
}

// ===========================================================================
// Output projection (r7 proven version, unchanged control). bf16 -> fp32.
// BM=64, BN=128, BK=64; grid 512. Waves 1x4 (64 x 32 each).
// ===========================================================================
__global__ __launch_bounds__(256, 2)
void gemm_out_b(const unsigned short* __restrict__ At,
                const unsigned short* __restrict__ wob,
                const float* __restrict__ bias, float* __restrict__ Cv) {
  const int K = 1024, N = 1024;
  __shared__ __align__(16) unsigned short As[64 * 64];
  __shared__ __align__(16) unsigned short Bs[128 * 64];
  const int bid = blockIdx.x;
  const int lbid = (bid & 7) * 64 + (bid >> 3);    // bijective, 512 = 8*64
  const int mb = lbid >> 3, nb = lbid & 7;
  const int tid = threadIdx.x;
  const int lane = tid & 63, w = tid >> 6;
  const int qc = lane & 15, g = lane >> 4;
  f32x4 acc[4][2] = {};

  const int lrow = lane >> 3, lg = lane & 7;
  const int gsrc = lg ^ lrow;
  const unsigned short* ag = At  + (size_t)(mb * 64 + w * 16 + lrow) * K + gsrc * 8;
  const unsigned short* bg = wob + (size_t)(nb * 128 + w * 32 + lrow) * K + gsrc * 8;
  unsigned short* al = &As[(w * 16) * 64];
  unsigned short* bl = &Bs[(w * 32) * 64];

  for (int kt = 0; kt < 16; ++kt) {
    __syncthreads();
#pragma unroll
    for (int i = 0; i < 2; ++i)
      gload16(ag + i * (8 * 1024) + kt * 64, al + (i * 8) * 64);
#pragma unroll
    for (int i = 0; i < 4; ++i)
      gload16(bg + i * (8 * 1024) + kt * 64, bl + (i * 8) * 64);
    __syncthreads();

    B8 af[4][2], bfr[2][2];
#pragma unroll
    for (int mi = 0; mi < 4; ++mi)
#pragma unroll
      for (int kk = 0; kk < 2; ++kk) {
        const int row = mi * 16 + qc;
        const int slot = ((kk << 2) + g) ^ (row & 7);
        af[mi][kk].u4 = *(const uint4*)&As[(row << 6) + (slot << 3)];
      }
#pragma unroll
    for (int ni = 0; ni < 2; ++ni)
#pragma unroll
      for (int kk = 0; kk < 2; ++kk) {
        const int row = w * 32 + ni * 16 + qc;
        const int slot = ((kk << 2) + g) ^ (row & 7);
        bfr[ni][kk].u4 = *(const uint4*)&Bs[(row << 6) + (slot << 3)];
      }
#pragma unroll
    for (int kk = 0; kk < 2; ++kk)
#pragma unroll
      for (int mi = 0; mi < 4; ++mi)
#pragma unroll
        for (int ni = 0; ni < 2; ++ni)
          acc[mi][ni] = mfma_bf16(af[mi][kk].v, bfr[ni][kk].v, acc[mi][ni]);
  }

#pragma unroll
  for (int ni = 0; ni < 2; ++ni) {
    const int col = nb * 128 + w * 32 + ni * 16 + qc;
    const float bv = bias[col];
#pragma unroll
    for (int mi = 0; mi < 4; ++mi) {
#pragma unroll
      for (int r = 0; r < 4; ++r) {
        const int row = mb * 64 + mi * 16 + g * 4 + r;
        Cv[(size_t)row * N + col] = acc[mi][ni][r] + bv;
      }
    }
  }
}

// ===========================================================================
// Causal flash attention + ALiBi v7: r11 structure + DOUBLE-BUFFERED K/V LDS
// (Ks/Vs 2x8KB each = 32KB total, still 4 blocks/CU). Per tile: SLOAD(t+1)
// -> FRAGX(buf cur) -> SWRITE(buf cur^1) -> ONE barrier (was two).
// Buffer offset via pointer arithmetic +cur*4096 (rule #20: no runtime
// array indexing). Swizzles/numerics identical to r11.
// ===========================================================================
__global__ __launch_bounds__(256, 4)
void flash_alibi(const unsigned short* __restrict__ Qp,
                 const unsigned short* __restrict__ Kp,
                 const unsigned short* __restrict__ Vt,
                 unsigned short* __restrict__ At) {
  const int S = 2048, Dm = 1024;
  const int bid0 = blockIdx.x;                       // 0..1023
  const int lbid = (bid0 & 7) * 128 + (bid0 >> 3);   // XCD-grouped, bijective
  const int z = lbid >> 5, y = lbid & 31;
  const int s = ((8 * (y & 3)) + (y >> 2) + 8 * (z & 3) + (z >> 2)) & 31;
  const int h = z & 15, b = z >> 4;
  const int tid = threadIdx.x, lane = tid & 63, w = tid >> 6;
  const int qc = lane & 15, g = lane >> 4;
  const int q0 = s * 64 + w * 16;
  const int qcol = q0 + qc;
  const float slope = exp2f(-(float)(h + 1));   // H=16 power-of-2 slopes
  const float L2E = 1.44269504f;
  const float ls1 = L2E * slope;
  const float THR = 11.54f;                      // 8 * log2(e)
  const size_t bS = (size_t)b * S;
  const int hoff = h * 64;
  const int ntile = s + 1;

  __shared__ __align__(16) unsigned short Ks[2][64 * 64];   // 16KB
  __shared__ __align__(16) unsigned short Vs[2][64 * 64];   // 16KB

  B8 qf[2];
  {
    const unsigned short* qa = Qp + (bS + qcol) * Dm + hoff + g * 8;
    qf[0].u4 = *(const uint4*)qa; qf[1].u4 = *(const uint4*)(qa + 32);
  }

  // --- staging: lane stages row w*16+qc; LDS slots gk0=g^q7 and gk0^4 hold
  //     LOGICAL granules g and g^4 (source offsets g*8 / (g^4)*8) ---
  const int q7 = qc & 7;
  const int gk0 = g ^ q7;
  const int gk1 = gk0 ^ 4;
  const int krow = w * 16 + qc;                  // tile-local row (K: kv, V: d)
  const unsigned short* kgA = Kp + (bS + krow) * Dm + hoff + g * 8;
  const unsigned short* kgB = Kp + (bS + krow) * Dm + hoff + (g ^ 4) * 8;
  const unsigned short* vgA =
      Vt + (((size_t)((b * 16 + h) * 64 + krow)) << 11) + g * 8;
  const unsigned short* vgB =
      Vt + (((size_t)((b * 16 + h) * 64 + krow)) << 11) + (g ^ 4) * 8;
  unsigned short* kwA = &Ks[0][krow * 64 + gk0 * 8];
  unsigned short* kwB = &Ks[0][krow * 64 + gk1 * 8];
  unsigned short* vwA = &Vs[0][krow * 64 + gk0 * 8];
  unsigned short* vwB = &Vs[0][krow * 64 + gk1 * 8];
  uint4 krA, krB, vrA, vrB;

#define SLOAD(TT) do {                                                         \
    const size_t ko_ = ((size_t)(TT) << 6) * Dm;                               \
    krA = *(const uint4*)(kgA + ko_); krB = *(const uint4*)(kgB + ko_);        \
    vrA = *(const uint4*)(vgA + ((TT) << 6));                                  \
    vrB = *(const uint4*)(vgB + ((TT) << 6));                                  \
  } while (0)
#define SWRITE(BO) do {                                                        \
    *(uint4*)(kwA + (BO)) = krA; *(uint4*)(kwB + (BO)) = krB;                  \
    *(uint4*)(vwA + (BO)) = vrA; *(uint4*)(vwB + (BO)) = vrB;                  \
  } while (0)

  // --- LDS read bases (buffer 0; +BO for buffer 1) ---
  const int sw = qc & 7;
  const unsigned short* krd0 = &Ks[0][qc * 64 + ((g ^ sw) << 3)];       // +f*1024
  const unsigned short* krd1 = &Ks[0][qc * 64 + (((g ^ sw) ^ 4) << 3)];
  const unsigned short* vrd[4];
#pragma unroll
  for (int j = 0; j < 4; ++j)
    vrd[j] = &Vs[0][qc * 64 + ((((2 * j) + (g >> 1)) ^ sw) << 3) + (g & 1) * 4];  // +n*1024

  f32x4 acc[4] = {};
  float m_run = 0.f, l_run = 0.f;
  const float abq = slope * (float)(g * 4 - qcol);

#define FRAGX(KV0, BO, MASKED) do {                                            \
    const float kv0f = (float)(KV0);                                           \
    f32x4 sc_[4] = {};                                                         \
    _Pragma("unroll")                                                          \
    for (int f_ = 0; f_ < 4; ++f_) {                                           \
      B8 k0_, k1_;                                                             \
      k0_.u4 = *(const uint4*)(krd0 + (BO) + f_ * 1024);                       \
      k1_.u4 = *(const uint4*)(krd1 + (BO) + f_ * 1024);                       \
      sc_[f_] = mfma_bf16(k0_.v, qf[0].v, sc_[f_]);                            \
      sc_[f_] = mfma_bf16(k1_.v, qf[1].v, sc_[f_]);                            \
    }                                                                          \
    const float cb_ = (fmaf(slope, kv0f, abq) - m_run) * L2E;                  \
    float ein_[4][4]; float emax_ = -1e30f;                                    \
    _Pragma("unroll")                                                          \
    for (int f_ = 0; f_ < 4; ++f_) {                                           \
      const float cf_ = cb_ + (float)(16 * f_) * ls1;                          \
      _Pragma("unroll")                                                        \
      for (int r_ = 0; r_ < 4; ++r_) {                                         \
        float e_ = fmaf(sc_[f_][r_], L2E, cf_ + (float)r_ * ls1);              \
        if (MASKED) {                                                          \
          const int kv_ = (KV0) + f_ * 16 + g * 4 + r_;                        \
          if (kv_ > qcol) e_ = -1e30f;                                         \
        }                                                                      \
        ein_[f_][r_] = e_; emax_ = fmaxf(emax_, e_);                           \
      }                                                                        \
    }                                                                          \
    if (!__all(emax_ <= THR)) {                                                \
      float er_ = fmaxf(emax_, __shfl_xor(emax_, 16));                         \
      er_ = fmaxf(er_, __shfl_xor(er_, 32));                                   \
      er_ = fmaxf(er_, 0.f);                                                   \
      m_run += er_ * 0.69314718f;                                              \
      const float sfac_ = EXP2F(-er_);                                         \
      l_run *= sfac_;                                                          \
      _Pragma("unroll") for (int n_ = 0; n_ < 4; ++n_) acc[n_] = acc[n_] * sfac_; \
      _Pragma("unroll") for (int f_ = 0; f_ < 4; ++f_)                         \
        _Pragma("unroll") for (int r_ = 0; r_ < 4; ++r_) ein_[f_][r_] -= er_;  \
    }                                                                          \
    B8 pf0_, pf1_; float lsum_ = 0.f;                                          \
    _Pragma("unroll")                                                          \
    for (int f_ = 0; f_ < 4; ++f_) {                                           \
      _Pragma("unroll")                                                        \
      for (int r_ = 0; r_ < 4; ++r_) {                                         \
        const float p_ = EXP2F(ein_[f_][r_]);                                  \
        lsum_ += p_;                                                           \
        if (f_ == 0)      pf0_.v[r_]     = (__bf16)p_;                         \
        else if (f_ == 1) pf0_.v[4 + r_] = (__bf16)p_;                         \
        else if (f_ == 2) pf1_.v[r_]     = (__bf16)p_;                         \
        else              pf1_.v[4 + r_] = (__bf16)p_;                         \
      }                                                                        \
    }                                                                          \
    l_run += lsum_;                                                            \
    _Pragma("unroll")                                                          \
    for (int n_ = 0; n_ < 4; ++n_) {                                           \
      B8 v0_, v1_;                                                             \
      uint2 a0_ = *(const uint2*)(vrd[0] + (BO) + n_ * 1024);                  \
      uint2 a1_ = *(const uint2*)(vrd[1] + (BO) + n_ * 1024);                  \
      uint2 a2_ = *(const uint2*)(vrd[2] + (BO) + n_ * 1024);                  \
      uint2 a3_ = *(const uint2*)(vrd[3] + (BO) + n_ * 1024);                  \
      v0_.u[0] = a0_.x; v0_.u[1] = a0_.y;                                      \
      v0_.u[2] = a1_.x; v0_.u[3] = a1_.y;                                      \
      v1_.u[0] = a2_.x; v1_.u[1] = a2_.y;                                      \
      v1_.u[2] = a3_.x; v1_.u[3] = a3_.y;                                      \
      acc[n_] = mfma_bf16(v0_.v, pf0_.v, acc[n_]);                             \
      acc[n_] = mfma_bf16(v1_.v, pf1_.v, acc[n_]);                             \
    }                                                                          \
  } while (0)

  SLOAD(0);
  SWRITE(0);
  __syncthreads();

  for (int t = 0; t < ntile - 1; ++t) {
    const int bo = (t & 1) << 12;          // 4096 elems per buffer
    SLOAD(t + 1);                           // global -> regs, issue early
    FRAGX(t << 6, bo, 0);                   // compute from buf[cur]
    SWRITE(bo ^ 4096);                      // write tile t+1 into buf[cur^1]
    __syncthreads();                        // ONE barrier per tile
  }
  FRAGX((ntile - 1) << 6, ((ntile - 1) & 1) << 12, 1);  // masked diagonal

  float lt = l_run + __shfl_xor(l_run, 16);
  lt += __shfl_xor(lt, 32);
  const float ri = 1.0f / lt;
  unsigned short* ob = At + (bS + qcol) * Dm + hoff;
#pragma unroll
  for (int n = 0; n < 4; ++n) {
    B4 ov;
    ov.v[0] = (__bf16)(acc[n][0] * ri);
    ov.v[1] = (__bf16)(acc[n][1] * ri);
    ov.v[2] = (__bf16)(acc[n][2] * ri);
    ov.v[3] = (__bf16)(acc[n][3] * ri);
    *(uint2*)(ob + n * 16 + g * 4) = ov.u2;
  }
}

extern "C" void kernel_launch(void* const* d_in, const int* in_sizes, int n_in,
                              void* d_out, int out_size, void* d_ws, size_t ws_size,
                              hipStream_t stream) {
  const float* q    = (const float*)d_in[0];
  const float* k    = (const float*)d_in[1];
  const float* v    = (const float*)d_in[2];
  // d_in[3] = causal mask, analytically known -> unused
  const float* wq_w = (const float*)d_in[4];
  const float* wq_b = (const float*)d_in[5];
  const float* wk_w = (const float*)d_in[6];
  const float* wk_b = (const float*)d_in[7];
  const float* wv_w = (const float*)d_in[8];
  const float* wv_b = (const float*)d_in[9];
  const float* ow   = (const float*)d_in[10];
  const float* ob   = (const float*)d_in[11];
  float* out = (float*)d_out;

  char* ws = (char*)d_ws;
  unsigned short* Qp = (unsigned short*)(ws);                  // 8MB [4096,1024]
  unsigned short* Kp = (unsigned short*)(ws + (8u << 20));     // 8MB
  unsigned short* Vt = (unsigned short*)(ws + (16u << 20));    // 8MB [B,H,64,2048]
  unsigned short* At = (unsigned short*)(ws + (24u << 20));    // 8MB [4096,1024]
  unsigned short* cvt = (unsigned short*)(ws + (32u << 20));   // 32MB contiguous
  unsigned short* qb  = cvt;                                    // 2^22 elems
  unsigned short* kb  = cvt + (1u << 22);
  unsigned short* vb  = cvt + (2u << 22);
  unsigned short* wqb = cvt + (3u << 22);
  unsigned short* wkb = wqb + (1u << 20);
  unsigned short* wvb = wkb + (1u << 20);
  unsigned short* wob = wvb + (1u << 20);

  dim3 blk(256);
  cvt_all<<<8192, blk, 0, stream>>>(q, k, v, wq_w, wk_w, wv_w, ow, cvt);
  gemm_qkv_b<<<1536, blk, 0, stream>>>(qb, kb, vb, wqb, wkb, wvb,
                                       wq_b, wk_b, wv_b, Qp, Kp, Vt);
  flash_alibi<<<1024, blk, 0, stream>>>(Qp, Kp, Vt, At);
  gemm_out_b<<<512, blk, 0, stream>>>(At, wob, ob, out);
}

// Round 15
// 123.230 us; speedup vs baseline: 1.0906x; 1.0906x over previous
//
#include <hip/hip_runtime.h>
#include <hip/hip_bf16.h>
#include <cstdint>
#include <cstddef>

#define DEV static __device__ __forceinline__

typedef float f32x4 __attribute__((ext_vector_type(4)));
typedef __bf16 bf16x8 __attribute__((ext_vector_type(8)));
typedef __bf16 bf16x4 __attribute__((ext_vector_type(4)));

#define EXP2F(x) __builtin_amdgcn_exp2f(x)

union B8 {
  uint4 u4;
  uint32_t u[4];
  unsigned short s[8];
  bf16x8 v;
};
union B4 {
  uint2 u2;
  unsigned short s[4];
  bf16x4 v;
};

DEV unsigned short bfbits(float x) {
  union { __bf16 h; unsigned short s; } z; z.h = (__bf16)x; return z.s;
}
DEV uint32_t pk2(float x, float y) {
  union { __bf16 h[2]; uint32_t u; } z;
  z.h[0] = (__bf16)x; z.h[1] = (__bf16)y; return z.u;
}

DEV f32x4 mfma_bf16(bf16x8 a, bf16x8 b, f32x4 c) {
  return __builtin_amdgcn_mfma_f32_16x16x32_bf16(a, b, c, 0, 0, 0);
}

// async global->LDS, 16B per lane; LDS dest = wave-uniform base + lane*16
DEV void gload16(const void* g, void* l) {
  __builtin_amdgcn_global_load_lds(
      (const __attribute__((address_space(1))) void*)g,
      (__attribute__((address_space(3))) void*)l, 16, 0, 0);
}

// ===========================================================================
// cvt_all: fp32 -> bf16 for q,k,v (2^22 each) + wq,wk,wv,ow (2^20 each)
// into one contiguous 2^24-elem bf16 region. Grid 8192 x 256; thread: 8 elems.
// ===========================================================================
__global__ __launch_bounds__(256)
void cvt_all(const float* __restrict__ q, const float* __restrict__ k,
             const float* __restrict__ v,
             const float* __restrict__ wq, const float* __restrict__ wk,
             const float* __restrict__ wv, const float* __restrict__ ow,
             unsigned short* __restrict__ dst) {
  const int bid = blockIdx.x;
  const size_t base = ((size_t)bid << 11) + ((size_t)threadIdx.x << 3);
  const float* src;
  size_t rel;
  if (bid < 2048)      { src = q; rel = base; }
  else if (bid < 4096) { src = k; rel = base - (1u << 22); }
  else if (bid < 6144) { src = v; rel = base - (2u << 22); }
  else {
    const int wseg = (bid - 6144) >> 9;
    src = wseg == 0 ? wq : wseg == 1 ? wk : wseg == 2 ? wv : ow;
    rel = base & 1048575u;
  }
  float4 a0 = *(const float4*)(src + rel);
  float4 a1 = *(const float4*)(src + rel + 4);
  B8 p;
  p.u[0] = pk2(a0.x, a0.y); p.u[1] = pk2(a0.z, a0.w);
  p.u[2] = pk2(a1.x, a1.y); p.u[3] = pk2(a1.z, a1.w);
  *(uint4*)(dst + base) = p.u4;
}

// ===========================================================================
// Fused QKV GEMM (r7/r11 proven: single-buffer, 2 barriers/kt, 32KB LDS,
// 3 blocks/CU, 48us). bf16 x bf16, global_load_lds, pre-swizzled source.
// Grid 768 = 3 proj x (32 mb x 8 nb), XCD-bijective swizzle.
// ===========================================================================
__global__ __launch_bounds__(256, 2)
void gemm_qkv_b(const unsigned short* __restrict__ qb,
                const unsigned short* __restrict__ kb,
                const unsigned short* __restrict__ vb,
                const unsigned short* __restrict__ wqb,
                const unsigned short* __restrict__ wkb,
                const unsigned short* __restrict__ wvb,
                const float* __restrict__ bq, const float* __restrict__ bk,
                const float* __restrict__ bv,
                unsigned short* __restrict__ Qp, unsigned short* __restrict__ Kp,
                unsigned short* __restrict__ Vt) {
  const int K = 1024, N = 1024;
  __shared__ __align__(16) unsigned short As[128 * 64];
  __shared__ __align__(16) unsigned short Bs[128 * 64];
  const int bid = blockIdx.x;
  const int lbid = (bid & 7) * 96 + (bid >> 3);    // bijective, 768 = 8*96
  const int proj = lbid >> 8;
  const int t = lbid & 255;
  const int mb = t >> 3, nb = t & 7;
  const unsigned short* A  = proj == 0 ? qb  : proj == 1 ? kb  : vb;
  const unsigned short* Bw = proj == 0 ? wqb : proj == 1 ? wkb : wvb;
  const float* bias        = proj == 0 ? bq  : proj == 1 ? bk  : bv;
  const int tid = threadIdx.x;
  const int lane = tid & 63, w = tid >> 6;
  const int wm = w >> 1, wn = w & 1;
  f32x4 acc[4][4] = {};

  const int lrow = lane >> 3;               // 0..7
  const int lg = lane & 7;
  const int gsrc = lg ^ lrow;               // pre-swizzled source granule
  const unsigned short* ag = A  + (size_t)(mb * 128 + w * 32 + lrow) * K + gsrc * 8;
  const unsigned short* bg = Bw + (size_t)(nb * 128 + w * 32 + lrow) * K + gsrc * 8;
  unsigned short* al = &As[(w * 32) * 64];
  unsigned short* bl = &Bs[(w * 32) * 64];

  for (int kt = 0; kt < 16; ++kt) {
    __syncthreads();
#pragma unroll
    for (int i = 0; i < 4; ++i) {
      gload16(ag + i * (8 * 1024) + kt * 64, al + (i * 8) * 64);
      gload16(bg + i * (8 * 1024) + kt * 64, bl + (i * 8) * 64);
    }
    __syncthreads();   // vmcnt drain -> tile visible

    B8 af[4][2], bfr[4][2];
#pragma unroll
    for (int mi = 0; mi < 4; ++mi)
#pragma unroll
      for (int kk = 0; kk < 2; ++kk) {
        const int row = wm * 64 + mi * 16 + (lane & 15);
        const int slot = ((kk << 2) + (lane >> 4)) ^ (row & 7);
        af[mi][kk].u4 = *(const uint4*)&As[(row << 6) + (slot << 3)];
      }
#pragma unroll
    for (int ni = 0; ni < 4; ++ni)
#pragma unroll
      for (int kk = 0; kk < 2; ++kk) {
        const int row = wn * 64 + ni * 16 + (lane & 15);
        const int slot = ((kk << 2) + (lane >> 4)) ^ (row & 7);
        bfr[ni][kk].u4 = *(const uint4*)&Bs[(row << 6) + (slot << 3)];
      }
#pragma unroll
    for (int kk = 0; kk < 2; ++kk)
#pragma unroll
      for (int mi = 0; mi < 4; ++mi)
#pragma unroll
        for (int ni = 0; ni < 4; ++ni)
          acc[mi][ni] = mfma_bf16(af[mi][kk].v, bfr[ni][kk].v, acc[mi][ni]);
  }

  unsigned short* Cv = proj == 0 ? Qp : proj == 1 ? Kp : Vt;
  const bool vt_mode = (proj == 2);
#pragma unroll
  for (int ni = 0; ni < 4; ++ni) {
    const int col = nb * 128 + wn * 64 + ni * 16 + (lane & 15);
    const float bv = bias[col];
#pragma unroll
    for (int mi = 0; mi < 4; ++mi) {
#pragma unroll
      for (int r = 0; r < 4; ++r) {
        const int row = mb * 128 + wm * 64 + mi * 16 + (lane >> 4) * 4 + r;
        const float val = acc[mi][ni][r] + bv;
        if (!vt_mode) {
          Cv[(size_t)row * N + col] = bfbits(val);
        } else {
          const int b = row >> 11, ss = row & 2047, hh = col >> 6, d = col & 63;
          Cv[((size_t)((b * 16 + hh) * 64 + d) << 11) + ss] = bfbits(val);
        }
      }
    }
  }
}

// ===========================================================================
// Output projection (r7 proven version). bf16 x bf16 -> fp32.
// BM=64, BN=128, BK=64; grid 512. Waves 1x4 (64 x 32 each).
// ===========================================================================
__global__ __launch_bounds__(256, 2)
void gemm_out_b(const unsigned short* __restrict__ At,
                const unsigned short* __restrict__ wob,
                const float* __restrict__ bias, float* __restrict__ Cv) {
  const int K = 1024, N = 1024;
  __shared__ __align__(16) unsigned short As[64 * 64];
  __shared__ __align__(16) unsigned short Bs[128 * 64];
  const int bid = blockIdx.x;
  const int lbid = (bid & 7) * 64 + (bid >> 3);    // bijective, 512 = 8*64
  const int mb = lbid >> 3, nb = lbid & 7;
  const int tid = threadIdx.x;
  const int lane = tid & 63, w = tid >> 6;
  const int qc = lane & 15, g = lane >> 4;
  f32x4 acc[4][2] = {};

  const int lrow = lane >> 3, lg = lane & 7;
  const int gsrc = lg ^ lrow;
  const unsigned short* ag = At  + (size_t)(mb * 64 + w * 16 + lrow) * K + gsrc * 8;
  const unsigned short* bg = wob + (size_t)(nb * 128 + w * 32 + lrow) * K + gsrc * 8;
  unsigned short* al = &As[(w * 16) * 64];
  unsigned short* bl = &Bs[(w * 32) * 64];

  for (int kt = 0; kt < 16; ++kt) {
    __syncthreads();
#pragma unroll
    for (int i = 0; i < 2; ++i)
      gload16(ag + i * (8 * 1024) + kt * 64, al + (i * 8) * 64);
#pragma unroll
    for (int i = 0; i < 4; ++i)
      gload16(bg + i * (8 * 1024) + kt * 64, bl + (i * 8) * 64);
    __syncthreads();

    B8 af[4][2], bfr[2][2];
#pragma unroll
    for (int mi = 0; mi < 4; ++mi)
#pragma unroll
      for (int kk = 0; kk < 2; ++kk) {
        const int row = mi * 16 + qc;
        const int slot = ((kk << 2) + g) ^ (row & 7);
        af[mi][kk].u4 = *(const uint4*)&As[(row << 6) + (slot << 3)];
      }
#pragma unroll
    for (int ni = 0; ni < 2; ++ni)
#pragma unroll
      for (int kk = 0; kk < 2; ++kk) {
        const int row = w * 32 + ni * 16 + qc;
        const int slot = ((kk << 2) + g) ^ (row & 7);
        bfr[ni][kk].u4 = *(const uint4*)&Bs[(row << 6) + (slot << 3)];
      }
#pragma unroll
    for (int kk = 0; kk < 2; ++kk)
#pragma unroll
      for (int mi = 0; mi < 4; ++mi)
#pragma unroll
        for (int ni = 0; ni < 2; ++ni)
          acc[mi][ni] = mfma_bf16(af[mi][kk].v, bfr[ni][kk].v, acc[mi][ni]);
  }

#pragma unroll
  for (int ni = 0; ni < 2; ++ni) {
    const int col = nb * 128 + w * 32 + ni * 16 + qc;
    const float bv = bias[col];
#pragma unroll
    for (int mi = 0; mi < 4; ++mi) {
#pragma unroll
      for (int r = 0; r < 4; ++r) {
        const int row = mb * 64 + mi * 16 + g * 4 + r;
        Cv[(size_t)row * N + col] = acc[mi][ni][r] + bv;
      }
    }
  }
}

// ===========================================================================
// Causal flash attention + ALiBi v5d: exact r11 structure (KVBLK=64,
// XCD-grouped lbid + balanced strip map, single-buffer, 50.4us proven) with
// ONE per-lane tweak: tree reductions for emax/lsum (depth 4 instead of 15
// serial ops; v_max3-fusable) -> shorter VALU dep chain per tile.
// ===========================================================================
__global__ __launch_bounds__(256, 4)
void flash_alibi(const unsigned short* __restrict__ Qp,
                 const unsigned short* __restrict__ Kp,
                 const unsigned short* __restrict__ Vt,
                 unsigned short* __restrict__ At) {
  const int S = 2048, Dm = 1024;
  const int bid0 = blockIdx.x;                       // 0..1023
  const int lbid = (bid0 & 7) * 128 + (bid0 >> 3);   // XCD-grouped, bijective
  const int z = lbid >> 5, y = lbid & 31;
  const int s = ((8 * (y & 3)) + (y >> 2) + 8 * (z & 3) + (z >> 2)) & 31;
  const int h = z & 15, b = z >> 4;
  const int tid = threadIdx.x, lane = tid & 63, w = tid >> 6;
  const int qc = lane & 15, g = lane >> 4;
  const int q0 = s * 64 + w * 16;
  const int qcol = q0 + qc;
  const float slope = exp2f(-(float)(h + 1));   // H=16 power-of-2 slopes
  const float L2E = 1.44269504f;
  const float ls1 = L2E * slope;
  const float THR = 11.54f;                      // 8 * log2(e)
  const size_t bS = (size_t)b * S;
  const int hoff = h * 64;
  const int ntile = s + 1;

  __shared__ __align__(16) unsigned short Ks[64 * 64];   // 8KB [kv][hd swz]
  __shared__ __align__(16) unsigned short Vs[64 * 64];   // 8KB [d][s swz]

  B8 qf[2];
  {
    const unsigned short* qa = Qp + (bS + qcol) * Dm + hoff + g * 8;
    qf[0].u4 = *(const uint4*)qa; qf[1].u4 = *(const uint4*)(qa + 32);
  }

  // --- staging: lane stages row w*16+qc; LDS slots gk0=g^q7 and gk0^4 hold
  //     LOGICAL granules g and g^4 (source offsets g*8 / (g^4)*8) ---
  const int q7 = qc & 7;
  const int gk0 = g ^ q7;
  const int gk1 = gk0 ^ 4;
  const int krow = w * 16 + qc;                  // tile-local row (K: kv, V: d)
  const unsigned short* kgA = Kp + (bS + krow) * Dm + hoff + g * 8;
  const unsigned short* kgB = Kp + (bS + krow) * Dm + hoff + (g ^ 4) * 8;
  const unsigned short* vgA =
      Vt + (((size_t)((b * 16 + h) * 64 + krow)) << 11) + g * 8;
  const unsigned short* vgB =
      Vt + (((size_t)((b * 16 + h) * 64 + krow)) << 11) + (g ^ 4) * 8;
  unsigned short* kwA = &Ks[krow * 64 + gk0 * 8];
  unsigned short* kwB = &Ks[krow * 64 + gk1 * 8];
  unsigned short* vwA = &Vs[krow * 64 + gk0 * 8];
  unsigned short* vwB = &Vs[krow * 64 + gk1 * 8];
  uint4 krA, krB, vrA, vrB;

#define SLOAD(TT) do {                                                         \
    const size_t ko_ = ((size_t)(TT) << 6) * Dm;                               \
    krA = *(const uint4*)(kgA + ko_); krB = *(const uint4*)(kgB + ko_);        \
    vrA = *(const uint4*)(vgA + ((TT) << 6));                                  \
    vrB = *(const uint4*)(vgB + ((TT) << 6));                                  \
  } while (0)
#define SWRITE() do {                                                          \
    *(uint4*)kwA = krA; *(uint4*)kwB = krB;                                    \
    *(uint4*)vwA = vrA; *(uint4*)vwB = vrB;                                    \
  } while (0)

  // --- LDS read bases (identical to r11) ---
  const int sw = qc & 7;
  const unsigned short* krd0 = &Ks[qc * 64 + ((g ^ sw) << 3)];          // +f*1024
  const unsigned short* krd1 = &Ks[qc * 64 + (((g ^ sw) ^ 4) << 3)];
  const unsigned short* vrd[4];
#pragma unroll
  for (int j = 0; j < 4; ++j)
    vrd[j] = &Vs[qc * 64 + ((((2 * j) + (g >> 1)) ^ sw) << 3) + (g & 1) * 4];  // +n*1024

  f32x4 acc[4] = {};
  float m_run = 0.f, l_run = 0.f;
  const float abq = slope * (float)(g * 4 - qcol);

#define FRAGX(KV0, MASKED) do {                                                \
    const float kv0f = (float)(KV0);                                           \
    f32x4 sc_[4] = {};                                                         \
    _Pragma("unroll")                                                          \
    for (int f_ = 0; f_ < 4; ++f_) {                                           \
      B8 k0_, k1_;                                                             \
      k0_.u4 = *(const uint4*)(krd0 + f_ * 1024);                              \
      k1_.u4 = *(const uint4*)(krd1 + f_ * 1024);                              \
      sc_[f_] = mfma_bf16(k0_.v, qf[0].v, sc_[f_]);                            \
      sc_[f_] = mfma_bf16(k1_.v, qf[1].v, sc_[f_]);                            \
    }                                                                          \
    const float cb_ = (fmaf(slope, kv0f, abq) - m_run) * L2E;                  \
    float ein_[4][4]; float fx_[4];                                            \
    _Pragma("unroll")                                                          \
    for (int f_ = 0; f_ < 4; ++f_) {                                           \
      const float cf_ = cb_ + (float)(16 * f_) * ls1;                          \
      _Pragma("unroll")                                                        \
      for (int r_ = 0; r_ < 4; ++r_) {                                         \
        float e_ = fmaf(sc_[f_][r_], L2E, cf_ + (float)r_ * ls1);              \
        if (MASKED) {                                                          \
          const int kv_ = (KV0) + f_ * 16 + g * 4 + r_;                        \
          if (kv_ > qcol) e_ = -1e30f;                                         \
        }                                                                      \
        ein_[f_][r_] = e_;                                                     \
      }                                                                        \
      fx_[f_] = fmaxf(fmaxf(ein_[f_][0], ein_[f_][1]),                         \
                      fmaxf(ein_[f_][2], ein_[f_][3]));                        \
    }                                                                          \
    const float emax_ = fmaxf(fmaxf(fx_[0], fx_[1]), fmaxf(fx_[2], fx_[3]));   \
    if (!__all(emax_ <= THR)) {                                                \
      float er_ = fmaxf(emax_, __shfl_xor(emax_, 16));                         \
      er_ = fmaxf(er_, __shfl_xor(er_, 32));                                   \
      er_ = fmaxf(er_, 0.f);                                                   \
      m_run += er_ * 0.69314718f;                                              \
      const float sfac_ = EXP2F(-er_);                                         \
      l_run *= sfac_;                                                          \
      _Pragma("unroll") for (int n_ = 0; n_ < 4; ++n_) acc[n_] = acc[n_] * sfac_; \
      _Pragma("unroll") for (int f_ = 0; f_ < 4; ++f_)                         \
        _Pragma("unroll") for (int r_ = 0; r_ < 4; ++r_) ein_[f_][r_] -= er_;  \
    }                                                                          \
    B8 pf0_, pf1_; float lp_[4];                                               \
    _Pragma("unroll")                                                          \
    for (int f_ = 0; f_ < 4; ++f_) {                                           \
      float p0_ = EXP2F(ein_[f_][0]);                                          \
      float p1_ = EXP2F(ein_[f_][1]);                                          \
      float p2_ = EXP2F(ein_[f_][2]);                                          \
      float p3_ = EXP2F(ein_[f_][3]);                                          \
      lp_[f_] = (p0_ + p1_) + (p2_ + p3_);                                     \
      if (f_ == 0) {                                                           \
        pf0_.v[0] = (__bf16)p0_; pf0_.v[1] = (__bf16)p1_;                      \
        pf0_.v[2] = (__bf16)p2_; pf0_.v[3] = (__bf16)p3_;                      \
      } else if (f_ == 1) {                                                    \
        pf0_.v[4] = (__bf16)p0_; pf0_.v[5] = (__bf16)p1_;                      \
        pf0_.v[6] = (__bf16)p2_; pf0_.v[7] = (__bf16)p3_;                      \
      } else if (f_ == 2) {                                                    \
        pf1_.v[0] = (__bf16)p0_; pf1_.v[1] = (__bf16)p1_;                      \
        pf1_.v[2] = (__bf16)p2_; pf1_.v[3] = (__bf16)p3_;                      \
      } else {                                                                 \
        pf1_.v[4] = (__bf16)p0_; pf1_.v[5] = (__bf16)p1_;                      \
        pf1_.v[6] = (__bf16)p2_; pf1_.v[7] = (__bf16)p3_;                      \
      }                                                                        \
    }                                                                          \
    l_run += (lp_[0] + lp_[1]) + (lp_[2] + lp_[3]);                            \
    _Pragma("unroll")                                                          \
    for (int n_ = 0; n_ < 4; ++n_) {                                           \
      B8 v0_, v1_;                                                             \
      uint2 a0_ = *(const uint2*)(vrd[0] + n_ * 1024);                         \
      uint2 a1_ = *(const uint2*)(vrd[1] + n_ * 1024);                         \
      uint2 a2_ = *(const uint2*)(vrd[2] + n_ * 1024);                         \
      uint2 a3_ = *(const uint2*)(vrd[3] + n_ * 1024);                         \
      v0_.u[0] = a0_.x; v0_.u[1] = a0_.y;                                      \
      v0_.u[2] = a1_.x; v0_.u[3] = a1_.y;                                      \
      v1_.u[0] = a2_.x; v1_.u[1] = a2_.y;                                      \
      v1_.u[2] = a3_.x; v1_.u[3] = a3_.y;                                      \
      acc[n_] = mfma_bf16(v0_.v, pf0_.v, acc[n_]);                             \
      acc[n_] = mfma_bf16(v1_.v, pf1_.v, acc[n_]);                             \
    }                                                                          \
  } while (0)

  SLOAD(0);
  SWRITE();
  __syncthreads();

  for (int t = 0; t < ntile - 1; ++t) {
    SLOAD(t + 1);            // issue early: latency hides under FRAGX
    FRAGX(t << 6, 0);
    __syncthreads();         // all waves done reading LDS tile t
    SWRITE();
    __syncthreads();         // tile t+1 visible
  }
  FRAGX((ntile - 1) << 6, 1);  // peeled masked diagonal tile

  float lt = l_run + __shfl_xor(l_run, 16);
  lt += __shfl_xor(lt, 32);
  const float ri = 1.0f / lt;
  unsigned short* ob = At + (bS + qcol) * Dm + hoff;
#pragma unroll
  for (int n = 0; n < 4; ++n) {
    B4 ov;
    ov.v[0] = (__bf16)(acc[n][0] * ri);
    ov.v[1] = (__bf16)(acc[n][1] * ri);
    ov.v[2] = (__bf16)(acc[n][2] * ri);
    ov.v[3] = (__bf16)(acc[n][3] * ri);
    *(uint2*)(ob + n * 16 + g * 4) = ov.u2;
  }
}

extern "C" void kernel_launch(void* const* d_in, const int* in_sizes, int n_in,
                              void* d_out, int out_size, void* d_ws, size_t ws_size,
                              hipStream_t stream) {
  const float* q    = (const float*)d_in[0];
  const float* k    = (const float*)d_in[1];
  const float* v    = (const float*)d_in[2];
  // d_in[3] = causal mask, analytically known -> unused
  const float* wq_w = (const float*)d_in[4];
  const float* wq_b = (const float*)d_in[5];
  const float* wk_w = (const float*)d_in[6];
  const float* wk_b = (const float*)d_in[7];
  const float* wv_w = (const float*)d_in[8];
  const float* wv_b = (const float*)d_in[9];
  const float* ow   = (const float*)d_in[10];
  const float* ob   = (const float*)d_in[11];
  float* out = (float*)d_out;

  char* ws = (char*)d_ws;
  unsigned short* Qp = (unsigned short*)(ws);                  // 8MB [4096,1024]
  unsigned short* Kp = (unsigned short*)(ws + (8u << 20));     // 8MB
  unsigned short* Vt = (unsigned short*)(ws + (16u << 20));    // 8MB [B,H,64,2048]
  unsigned short* At = (unsigned short*)(ws + (24u << 20));    // 8MB [4096,1024]
  unsigned short* cvt = (unsigned short*)(ws + (32u << 20));   // 32MB contiguous
  unsigned short* qb  = cvt;                                    // 2^22 elems
  unsigned short* kb  = cvt + (1u << 22);
  unsigned short* vb  = cvt + (2u << 22);
  unsigned short* wqb = cvt + (3u << 22);
  unsigned short* wkb = wqb + (1u << 20);
  unsigned short* wvb = wkb + (1u << 20);
  unsigned short* wob = wvb + (1u << 20);

  dim3 blk(256);
  cvt_all<<<8192, blk, 0, stream>>>(q, k, v, wq_w, wk_w, wv_w, ow, cvt);
  gemm_qkv_b<<<768, blk, 0, stream>>>(qb, kb, vb, wqb, wkb, wvb,
                                      wq_b, wk_b, wv_b, Qp, Kp, Vt);
  flash_alibi<<<1024, blk, 0, stream>>>(Qp, Kp, Vt, At);
  gemm_out_b<<<512, blk, 0, stream>>>(At, wob, ob, out);
}